// Round 8
// baseline (794.586 us; speedup 1.0000x reference)
//
#include <hip/hip_runtime.h>
#include <cstdint>
#include <cstddef>

#define NB 4
#define NS 1024
#define ND 512
#define NH 8
#define NLAYER 2
#define NDFF 2048

typedef __attribute__((ext_vector_type(8))) short short8;
typedef __attribute__((ext_vector_type(4))) float f32x4;
typedef __attribute__((ext_vector_type(4))) unsigned short u16x4;
typedef unsigned short u16;
typedef long long ll;

__device__ __forceinline__ float b2f(u16 u) {
  union { unsigned int i; float f; } x; x.i = ((unsigned int)u) << 16; return x.f;
}
__device__ __forceinline__ u16 f2b(float f) {  // RNE fp32 -> bf16
  union { float f; unsigned int i; } x; x.f = f;
  return (u16)((x.i + 0x7FFF + ((x.i >> 16) & 1)) >> 16);
}

struct Zm { int div; ll hi, lo; };   // per-z offset = (z/div)*hi + (z%div)*lo
__device__ __forceinline__ ll zoff(Zm m, int z) {
  return (ll)(z / m.div) * m.hi + (ll)(z % m.div) * m.lo;
}

enum { F_BF16 = 1, F_RELU = 2, F_BCOL = 4, F_BROW = 8, F_RESID = 16 };

// async global->LDS, 16B/lane; LDS dest is wave-uniform base + lane*16 (m104).
__device__ __forceinline__ void load_lds16(const void* g, void* s) {
  __builtin_amdgcn_global_load_lds(
      (const __attribute__((address_space(1))) void*)(uintptr_t)g,
      (__attribute__((address_space(3))) void*)(uint32_t)(uintptr_t)s, 16, 0, 0);
}

#define MFMA16(d, a, b) \
  asm volatile("v_mfma_f32_16x16x32_bf16 %0, %1, %2, %0" : "+v"(d) : "v"(a), "v"(b))
#define WAITVM(n) asm volatile("s_waitcnt vmcnt(" #n ")" ::: "memory")
#define BAR() __builtin_amdgcn_s_barrier()

// ---------------------------------------------------------------------------
// BT-form GEMM (round-3 verified): C[m,n] = scale*sum_k A[m,k]*B[n,k]
// 128x128 tile, BK=32 dbuf, 4 waves 2x2, one barrier per K-step.
// z>=zsplit selects Bw2/bias2. flags==0 -> raw fp32 (split-K partial).
// ---------------------------------------------------------------------------
__global__ void __launch_bounds__(256)
gemm_bt(const u16* __restrict__ A, int lda, Zm za,
        const u16* __restrict__ Bw, int ldb, Zm zb,
        const u16* __restrict__ Bw2, const float* __restrict__ bias2, int zsplit,
        void* __restrict__ Cv, int ldc, Zm zc,
        const float* __restrict__ bias, Zm zbias,
        const float* __restrict__ resid,
        float scale, int K, int flags)
{
  __shared__ __align__(16) char smem[2][16384];   // [buf][A:0..8191 | B:8192..]

  const int gx = gridDim.x, gy = gridDim.y;
  int id = (blockIdx.z * gy + blockIdx.y) * gx + blockIdx.x;
  const int nwg = gx * gy * (int)gridDim.z;
  if ((nwg & 7) == 0) id = (id & 7) * (nwg >> 3) + (id >> 3);
  const int bx = id % gx;
  const int rest = id / gx;
  const int by = rest % gy;
  const int z0 = rest / gy;

  int zB = z0;
  const u16* Bsel = Bw;
  const float* bsel = bias;
  if (z0 >= zsplit) { Bsel = Bw2; bsel = bias2; zB = z0 - zsplit; }

  A    += zoff(za, z0);
  Bsel += zoff(zb, zB);

  const int bm = by * 128, bn = bx * 128;
  const int t = threadIdx.x;
  const int w = t >> 6, lane = t & 63;
  const int wr = w >> 1, wc = w & 1;

  const u16* ga0 = A    + (size_t)(bm + (t >> 2)) * lda + ((t & 3) << 3);
  const u16* ga1 = ga0 + (size_t)64 * lda;
  const u16* gb0 = Bsel + (size_t)(bn + (t >> 2)) * ldb + ((t & 3) << 3);
  const u16* gb1 = gb0 + (size_t)64 * ldb;

  auto STAGE = [&](int sel, int kt) {
    const int k0 = kt << 5;
    char* sa = smem[sel] + (w << 10);
    char* sb = smem[sel] + 8192 + (w << 10);
    load_lds16(ga0 + k0, sa);
    load_lds16(ga1 + k0, sa + 4096);
    load_lds16(gb0 + k0, sb);
    load_lds16(gb1 + k0, sb + 4096);
  };

  f32x4 acc[4][4];
#pragma unroll
  for (int i = 0; i < 4; ++i)
#pragma unroll
    for (int j = 0; j < 4; ++j) acc[i][j] = (f32x4){0.f, 0.f, 0.f, 0.f};

  const int fr = lane & 15;
  const int kg = (lane >> 4) << 3;

  const int nt = K >> 5;
  STAGE(0, 0);
  __syncthreads();
  int cur = 0;
  for (int kt = 0; kt < nt; ++kt) {
    if (kt + 1 < nt) STAGE(cur ^ 1, kt + 1);
    const u16* la = (const u16*)smem[cur];
    const u16* lb = (const u16*)(smem[cur] + 8192);
    short8 af[4], bf[4];
#pragma unroll
    for (int mi = 0; mi < 4; ++mi)
      af[mi] = *(const short8*)(la + (wr * 64 + mi * 16 + fr) * 32 + kg);
#pragma unroll
    for (int ni = 0; ni < 4; ++ni)
      bf[ni] = *(const short8*)(lb + (wc * 64 + ni * 16 + fr) * 32 + kg);
#pragma unroll
    for (int mi = 0; mi < 4; ++mi)
#pragma unroll
      for (int ni = 0; ni < 4; ++ni)
        MFMA16(acc[mi][ni], af[mi], bf[ni]);
    __syncthreads();
    cur ^= 1;
  }

  asm volatile("s_nop 7\n\ts_nop 7" ::: "memory");

  const ll co = zoff(zc, z0);
  const float* bz = (flags & (F_BCOL | F_BROW)) ? bsel + zoff(zbias, zB) : nullptr;
  const int r0 = (lane >> 4) << 2;
  const int c0 = lane & 15;
#pragma unroll
  for (int mi = 0; mi < 4; ++mi) {
#pragma unroll
    for (int ni = 0; ni < 4; ++ni) {
#pragma unroll
      for (int r = 0; r < 4; ++r) {
        const int grow = bm + wr * 64 + mi * 16 + r0 + r;
        const int gcol = bn + wc * 64 + ni * 16 + c0;
        float v = acc[mi][ni][r] * scale;
        if (flags & F_BCOL) v += bz[gcol];
        if (flags & F_BROW) v += bz[grow];
        if (flags & F_RELU) v = fmaxf(v, 0.f);
        if (flags & F_RESID) v += resid[(size_t)grow * ldc + gcol];
        const ll idx = co + (ll)grow * ldc + gcol;
        if (flags & F_BF16) ((u16*)Cv)[idx] = f2b(v);
        else                ((float*)Cv)[idx] = v;
      }
    }
  }
}

// ---------------------------------------------------------------------------
// Fused flash attention v3. Grid 512 = 32 (h,b) x 16 q-tiles of 64 rows.
// 256 thr / 4 waves; wave owns 16 q rows (softmax wave-local). Q in regs.
// KV-tile 64. 3 rotating 16KB buffers; 8 phases/kv (4 K d-chunks, 4 vT
// e-chunks), each phase: WAITVM(4) -> raw BAR -> issue stage(g+2) -> reads +
// 16 MFMA. Loads get ~2 phases (+softmax) of cover; vmcnt never drains to 0
// in the loop (T4). p_lds stride 72 u16 (144B: 16B-aligned, odd*16 -> khi
// groups decorrelate across banks). Softmax between QK and PV = extra cover.
// LDS 57.2KB -> 2 blocks/CU (= grid cap).
// ---------------------------------------------------------------------------
__global__ void __launch_bounds__(256)
fattn(const u16* __restrict__ qg, const u16* __restrict__ kg,
      const u16* __restrict__ vtg, u16* __restrict__ cat)
{
  __shared__ __align__(16) u16 stg[3][64 * 128];   // 3 x 16KB rotating
  __shared__ __align__(16) u16 p_lds[64 * 72];     // 9.2KB, stride 72

  int id = blockIdx.x;
  id = (id & 7) * 64 + (id >> 3);            // XCD-chunk: same hb on one XCD
  const int qt = id & 15;
  const int hb = id >> 4;                    // h*4 + b
  const int h = hb >> 2, b = hb & 3;

  const ll hbase = (ll)h * NB * NS * ND;
  const u16* Q  = qg  + hbase + (ll)(b * NS + qt * 64) * ND;
  const u16* Kp = kg  + hbase + (ll)b * NS * ND;
  const u16* VT = vtg + (ll)hb * ND * NS;    // [e][t], ld NS
  u16* Op = cat + (ll)(b * NS + qt * 64) * (NH * ND) + h * ND;

  const int t = threadIdx.x;
  const int w = t >> 6, lane = t & 63;
  const int fr = lane & 15, khi = lane >> 4;

  // ---- Q in registers: qreg[s] = Q[w*16+fr][32s + 8khi .. +7], s=0..15 ----
  short8 qreg[16];
#pragma unroll
  for (int s = 0; s < 16; ++s)
    qreg[s] = *(const short8*)(Q + (ll)(w * 16 + fr) * ND + s * 32 + khi * 8);

  // ---- staging geometry (pre-swizzled global source, linear LDS dest) ----
  const int srowK = t >> 4;                          // K chunk: 16 granules/row
  const int scolK = (((t & 15) ^ (srowK & 7)) << 3); // u16 units
  const int srowV = t >> 3;                          // vT chunk: 8 granules/row
  const int scolV = (((t & 7) ^ (srowV & 7)) << 3);
  const int wofs = w << 10;

  auto STG_K = [&](int buf, int kv, int dch) {       // K[kv*64..+64)[dch*128..+128)
#pragma unroll
    for (int i = 0; i < 4; ++i)
      load_lds16(Kp + (ll)(kv * 64 + i * 16 + srowK) * ND + dch * 128 + scolK,
                 (char*)stg[buf] + i * 4096 + wofs);
  };
  auto STG_V = [&](int buf, int kv, int ec) {        // vT[ec*128..+128)[kv*64..+64)
#pragma unroll
    for (int i = 0; i < 4; ++i)
      load_lds16(VT + (ll)(ec * 128 + i * 32 + srowV) * NS + kv * 64 + scolV,
                 (char*)stg[buf] + i * 4096 + wofs);
  };
  auto STAGE_PH = [&](int g) {                       // phase g's data, buffer g%3
    const int kvv = g >> 3, pp = g & 7;
    if (kvv >= 16) return;
    if (pp < 4) STG_K(g % 3, kvv, pp);
    else        STG_V(g % 3, kvv, pp - 4);
  };

  f32x4 o[4][8];                                     // [ec][nf] : 16q x 512e
#pragma unroll
  for (int ec = 0; ec < 4; ++ec)
#pragma unroll
    for (int nf = 0; nf < 8; ++nf) o[ec][nf] = (f32x4){0.f, 0.f, 0.f, 0.f};
  float m_r[4] = {-1e30f, -1e30f, -1e30f, -1e30f};
  float l_r[4] = {0.f, 0.f, 0.f, 0.f};

  STAGE_PH(0);
  STAGE_PH(1);

  for (int kv = 0; kv < 16; ++kv) {
    // ---------------- QK^T: 4 phases (K d-chunks of 128) ----------------
    f32x4 s[4];
#pragma unroll
    for (int nf = 0; nf < 4; ++nf) s[nf] = (f32x4){0.f, 0.f, 0.f, 0.f};

#pragma unroll
    for (int p = 0; p < 4; ++p) {
      WAITVM(4);                       // phase data landed; next phase in flight
      BAR();
      STAGE_PH(kv * 8 + p + 2);
      const u16* kb_ = stg[(kv * 8 + p) % 3];
#pragma unroll
      for (int ks = 0; ks < 4; ++ks) {
        const short8 aq = qreg[p * 4 + ks];
#pragma unroll
        for (int nf = 0; nf < 4; ++nf) {
          const short8 bk = *(const short8*)(
              kb_ + (nf * 16 + fr) * 128 + (((4 * ks + khi) ^ (fr & 7)) << 3));
          MFMA16(s[nf], aq, bk);
        }
      }
    }
    asm volatile("s_nop 7\n\ts_nop 7" ::: "memory");   // MFMA->VALU hazard

    // -------- online softmax (rows 4khi+r wave-local; T13 defer-max) --------
    float mxs[4];
    bool big = false;
#pragma unroll
    for (int r = 0; r < 4; ++r) {
      float mx = s[0][r];
#pragma unroll
      for (int nf = 1; nf < 4; ++nf) mx = fmaxf(mx, s[nf][r]);
      mx *= 0.125f;
      mx = fmaxf(mx, __shfl_xor(mx, 1));
      mx = fmaxf(mx, __shfl_xor(mx, 2));
      mx = fmaxf(mx, __shfl_xor(mx, 4));
      mx = fmaxf(mx, __shfl_xor(mx, 8));
      mxs[r] = mx;
      big = big || (mx > m_r[r] + 8.f);
    }
    const bool resc = __any(big);
    float f_r[4];
#pragma unroll
    for (int r = 0; r < 4; ++r) {
      const float mn = resc ? fmaxf(m_r[r], mxs[r]) : m_r[r];
      f_r[r] = resc ? __expf(m_r[r] - mn) : 1.f;
      m_r[r] = mn;
      float sum = 0.f;
      const int R = w * 16 + 4 * khi + r;
#pragma unroll
      for (int nf = 0; nf < 4; ++nf) {
        const float e = __expf(s[nf][r] * 0.125f - mn);
        sum += e;
        p_lds[R * 72 + nf * 16 + fr] = f2b(e);
      }
      sum += __shfl_xor(sum, 1);
      sum += __shfl_xor(sum, 2);
      sum += __shfl_xor(sum, 4);
      sum += __shfl_xor(sum, 8);
      l_r[r] = l_r[r] * f_r[r] + sum;
    }
    if (resc) {
#pragma unroll
      for (int ec = 0; ec < 4; ++ec)
#pragma unroll
        for (int nf = 0; nf < 8; ++nf)
#pragma unroll
          for (int r = 0; r < 4; ++r) o[ec][nf][r] *= f_r[r];
    }

    // p write -> ap read is intra-wave: fence LDS order (rule 18)
    asm volatile("s_waitcnt lgkmcnt(0)" ::: "memory");
    __builtin_amdgcn_sched_barrier(0);
    short8 ap[2];
#pragma unroll
    for (int ks2 = 0; ks2 < 2; ++ks2)
      ap[ks2] = *(const short8*)(p_lds + (w * 16 + fr) * 72 + 32 * ks2 + 8 * khi);

    // ---------------- PV: 4 phases (vT e-chunks of 128) ----------------
#pragma unroll
    for (int p2 = 0; p2 < 4; ++p2) {
      if (kv == 15 && p2 == 3) { WAITVM(0); } else { WAITVM(4); }
      BAR();
      STAGE_PH(kv * 8 + 4 + p2 + 2);
      const u16* vb = stg[(kv * 8 + 4 + p2) % 3];
#pragma unroll
      for (int ks2 = 0; ks2 < 2; ++ks2)
#pragma unroll
        for (int nf = 0; nf < 8; ++nf) {
          const short8 bv = *(const short8*)(
              vb + (nf * 16 + fr) * 64 + (((4 * ks2 + khi) ^ (fr & 7)) << 3));
          MFMA16(o[p2][nf], ap[ks2], bv);
        }
    }
  }

  asm volatile("s_nop 7\n\ts_nop 7" ::: "memory");
#pragma unroll
  for (int r = 0; r < 4; ++r) {
    const float inv = 1.f / l_r[r];
    const ll row = (ll)(w * 16 + 4 * khi + r) * (NH * ND);
#pragma unroll
    for (int ec = 0; ec < 4; ++ec)
#pragma unroll
      for (int nf = 0; nf < 8; ++nf)
        Op[row + ec * 128 + nf * 16 + fr] = f2b(o[ec][nf][r] * inv);
  }
}

// fused split-K reduce + bias + residual + LayerNorm; one wave/row, 4 rows/blk
__global__ void __launch_bounds__(256)
ln_red(const float* __restrict__ parts, int np, ll pstride,
       const float* __restrict__ bias, const float* __restrict__ resid,
       const float* __restrict__ g, const float* __restrict__ be,
       float* __restrict__ xout, u16* __restrict__ xbout)
{
  const int t = threadIdx.x, w = t >> 6, lane = t & 63;
  const ll row = (ll)blockIdx.x * 4 + w;
  const ll base = row * ND + lane * 8;
  float v[8];
  *(f32x4*)(v)     = *(const f32x4*)(resid + base);
  *(f32x4*)(v + 4) = *(const f32x4*)(resid + base + 4);
#pragma unroll
  for (int j = 0; j < 8; ++j) v[j] += bias[lane * 8 + j];
  for (int pIdx = 0; pIdx < np; ++pIdx) {
    const float* pp = parts + pIdx * pstride + base;
    f32x4 a0 = *(const f32x4*)(pp);
    f32x4 a1 = *(const f32x4*)(pp + 4);
    v[0] += a0.x; v[1] += a0.y; v[2] += a0.z; v[3] += a0.w;
    v[4] += a1.x; v[5] += a1.y; v[6] += a1.z; v[7] += a1.w;
  }
  float s = 0.f, q = 0.f;
#pragma unroll
  for (int j = 0; j < 8; ++j) { s += v[j]; q += v[j] * v[j]; }
#pragma unroll
  for (int o = 32; o >= 1; o >>= 1) { s += __shfl_xor(s, o); q += __shfl_xor(q, o); }
  const float mean = s * (1.f / ND);
  const float var  = q * (1.f / ND) - mean * mean;
  const float inv  = 1.f / sqrtf(var + 1e-5f);
#pragma unroll
  for (int j = 0; j < 8; ++j) {
    const int c = lane * 8 + j;
    const float y = (v[j] - mean) * inv * g[c] + be[c];
    xout[row * ND + c] = y;
    xbout[row * ND + c] = f2b(y);
  }
}

struct CvtJobs { const float* src[7]; u16* dst[7]; ll n[7]; };

__global__ void __launch_bounds__(256)
cvt7(CvtJobs j)
{
  const int z = blockIdx.y;
  const ll i = ((ll)blockIdx.x * 256 + threadIdx.x) * 4;
  if (i >= j.n[z]) return;
  f32x4 v = *(const f32x4*)(j.src[z] + i);
  u16x4 o;
  o.x = f2b(v.x); o.y = f2b(v.y); o.z = f2b(v.z); o.w = f2b(v.w);
  *(u16x4*)(j.dst[z] + i) = o;
}

// ---------------------------------------------------------------------------
extern "C" void kernel_launch(void* const* d_in, const int* in_sizes, int n_in,
                              void* d_out, int out_size, void* d_ws, size_t ws_size,
                              hipStream_t stream)
{
  (void)in_sizes; (void)n_in; (void)out_size; (void)ws_size;
  const float* x_in = (const float*)d_in[0];
  const float* Wq = (const float*)d_in[1];  const float* bq = (const float*)d_in[2];
  const float* Wk = (const float*)d_in[3];  const float* bk = (const float*)d_in[4];
  const float* Wv = (const float*)d_in[5];  const float* bv = (const float*)d_in[6];
  const float* Wo = (const float*)d_in[7];  const float* bo = (const float*)d_in[8];
  const float* W1 = (const float*)d_in[9];  const float* b1 = (const float*)d_in[10];
  const float* W2 = (const float*)d_in[11]; const float* b2 = (const float*)d_in[12];
  const float* ln1g = (const float*)d_in[13]; const float* ln1b = (const float*)d_in[14];
  const float* ln2g = (const float*)d_in[15]; const float* ln2b = (const float*)d_in[16];

  char* p = (char*)d_ws;
  auto alloc = [&](ll bytes) { char* r = p; p += (bytes + 255) & ~(ll)255; return r; };
  const ll nWq = (ll)NLAYER * NH * ND * ND;
  const ll nWo = (ll)NLAYER * ND * NH * ND;
  const ll nW1 = (ll)NLAYER * NDFF * ND;
  const ll nX  = (ll)NB * NS * ND;

  u16* wq_b = (u16*)alloc(nWq * 2);   // wq_b/wk_b adjacent, qb/kb adjacent
  u16* wk_b = (u16*)alloc(nWq * 2);
  u16* wv_b = (u16*)alloc(nWq * 2);
  u16* wo_b = (u16*)alloc(nWo * 2);
  u16* w1_b = (u16*)alloc(nW1 * 2);
  u16* w2_b = (u16*)alloc(nW1 * 2);
  u16* xb   = (u16*)alloc(nX * 2);
  u16* qb   = (u16*)alloc((ll)NH * NB * NS * ND * 2);  // [h][b*s][e]
  u16* kb   = (u16*)alloc((ll)NH * NB * NS * ND * 2);  // LIVE through fattn
  u16* vT   = (u16*)alloc((ll)NH * NB * ND * NS * 2);  // [h][b][e][t]
  u16* scb  = (u16*)alloc((ll)NB * NH * NS * NS * 2);  // cat (33.5MB) + parts (33.5MB)
  u16* cat = scb;                                      // [b][s][h*512+e]
  float* parts = (float*)(scb + (ll)NB * NS * NH * ND);
  u16* ffh = qb;                                       // overlay: q dead after fattn

  CvtJobs cj;
  cj.src[0] = Wq; cj.dst[0] = wq_b; cj.n[0] = nWq;
  cj.src[1] = Wk; cj.dst[1] = wk_b; cj.n[1] = nWq;
  cj.src[2] = Wv; cj.dst[2] = wv_b; cj.n[2] = nWq;
  cj.src[3] = Wo; cj.dst[3] = wo_b; cj.n[3] = nWo;
  cj.src[4] = W1; cj.dst[4] = w1_b; cj.n[4] = nW1;
  cj.src[5] = W2; cj.dst[5] = w2_b; cj.n[5] = nW1;
  cj.src[6] = x_in; cj.dst[6] = xb; cj.n[6] = nX;
  cvt7<<<dim3((unsigned)((nWq / 4 + 255) / 256), 7), 256, 0, stream>>>(cj);

  float* xf = (float*)d_out;           // fp32 residual stream lives in d_out
  const Zm Z0{1, 0, 0};
  const ll PSTR = nX;                  // split-K partial stride (elements)
  const int ZINF = 1 << 30;

  for (int i = 0; i < NLAYER; ++i) {
    const float* resid1 = (i == 0) ? x_in : xf;
    const ll woff = (ll)i * NH * ND * ND;

    // q+k projections merged: z<8 -> Wq/bq, z>=8 -> Wk/bk (C runs qb into kb)
    gemm_bt<<<dim3(ND/128, (NB*NS)/128, 2*NH), 256, 0, stream>>>(
        xb, ND, Z0,
        wq_b + woff, ND, Zm{1, (ll)ND * ND, 0},
        wk_b + woff, bk + (ll)i * NH * ND, NH,
        qb, ND, Zm{1, (ll)NB * NS * ND, 0},
        bq + (ll)i * NH * ND, Zm{1, ND, 0}, nullptr, 1.f, ND, F_BF16 | F_BCOL);

    // vT projection (operands swapped -> transposed out): z=h*4+b, C[e][t]
    gemm_bt<<<dim3(NS/128, ND/128, NH*NB), 256, 0, stream>>>(
        wv_b + woff, ND, Zm{NB, (ll)ND * ND, 0},
        xb, ND, Zm{NB, 0, (ll)NS * ND},
        xb, nullptr, ZINF,
        vT, NS, Zm{1, (ll)ND * NS, 0},
        bv + (ll)i * NH * ND, Zm{NB, ND, 0}, nullptr, 1.f, ND, F_BF16 | F_BROW);

    // fused flash attention: scores+softmax+PV -> cat
    fattn<<<dim3(512), 256, 0, stream>>>(qb, kb, vT, cat);

    // mha_out partials: split-K over K=4096 into 4 chunks of 1024
    gemm_bt<<<dim3(ND/128, (NB*NS)/128, 4), 256, 0, stream>>>(
        cat, NH * ND, Zm{1, 1024, 0},
        wo_b + (ll)i * ND * NH * ND, NH * ND, Zm{1, 1024, 0},
        wo_b, nullptr, ZINF,
        parts, ND, Zm{1, PSTR, 0},
        nullptr, Z0, nullptr, 1.f, 1024, 0);

    // LN1 = LayerNorm(resid + bo + sum parts)
    ln_red<<<dim3(NB * NS / 4), 256, 0, stream>>>(
        parts, 4, PSTR, bo + (ll)i * ND, resid1,
        ln1g + (ll)i * ND, ln1b + (ll)i * ND, xf, xb);

    // ffh = relu(x @ W1^T + b1)  (bf16)
    gemm_bt<<<dim3(NDFF/128, (NB*NS)/128, 1), 256, 0, stream>>>(
        xb, ND, Z0,
        w1_b + (ll)i * NDFF * ND, ND, Z0,
        w1_b, nullptr, ZINF,
        ffh, NDFF, Z0,
        b1 + (ll)i * NDFF, Z0, nullptr, 1.f, ND, F_BF16 | F_BCOL | F_RELU);

    // ff partials: split-K over K=2048 into 4 chunks of 512
    gemm_bt<<<dim3(ND/128, (NB*NS)/128, 4), 256, 0, stream>>>(
        ffh, NDFF, Zm{1, 512, 0},
        w2_b + (ll)i * ND * NDFF, NDFF, Zm{1, 512, 0},
        w2_b, nullptr, ZINF,
        parts, ND, Zm{1, PSTR, 0},
        nullptr, Z0, nullptr, 1.f, 512, 0);

    // LN2 = LayerNorm(x + b2 + sum parts)
    ln_red<<<dim3(NB * NS / 4), 256, 0, stream>>>(
        parts, 4, PSTR, b2 + (ll)i * ND, xf,
        ln2g + (ll)i * ND, ln2b + (ll)i * ND, xf, xb);
  }
}

// Round 9
// 708.251 us; speedup vs baseline: 1.1219x; 1.1219x over previous
//
#include <hip/hip_runtime.h>
#include <cstdint>
#include <cstddef>

#define NB 4
#define NS 1024
#define ND 512
#define NH 8
#define NLAYER 2
#define NDFF 2048

typedef __attribute__((ext_vector_type(8))) short short8;
typedef __attribute__((ext_vector_type(4))) float f32x4;
typedef __attribute__((ext_vector_type(4))) unsigned short u16x4;
typedef unsigned short u16;
typedef long long ll;

__device__ __forceinline__ float b2f(u16 u) {
  union { unsigned int i; float f; } x; x.i = ((unsigned int)u) << 16; return x.f;
}
__device__ __forceinline__ u16 f2b(float f) {  // RNE fp32 -> bf16
  union { float f; unsigned int i; } x; x.f = f;
  return (u16)((x.i + 0x7FFF + ((x.i >> 16) & 1)) >> 16);
}

struct Zm { int div; ll hi, lo; };   // per-z offset = (z/div)*hi + (z%div)*lo
__device__ __forceinline__ ll zoff(Zm m, int z) {
  return (ll)(z / m.div) * m.hi + (ll)(z % m.div) * m.lo;
}

enum { F_BF16 = 1, F_RELU = 2, F_BCOL = 4, F_BROW = 8, F_RESID = 16 };

// async global->LDS, 16B/lane; LDS dest is wave-uniform base + lane*16 (m104).
__device__ __forceinline__ void load_lds16(const void* g, void* s) {
  __builtin_amdgcn_global_load_lds(
      (const __attribute__((address_space(1))) void*)(uintptr_t)g,
      (__attribute__((address_space(3))) void*)(uint32_t)(uintptr_t)s, 16, 0, 0);
}

#define MFMA16(d, a, b) \
  asm volatile("v_mfma_f32_16x16x32_bf16 %0, %1, %2, %0" : "+v"(d) : "v"(a), "v"(b))

// ---------------------------------------------------------------------------
// BT-form GEMM v6: C[m,n] = scale*sum_k A[m,k]*B[n,k]  (+bias/relu/resid)
// 128x64 tile, BK=32, 4 waves 2x2 (wave = 64x32 out -> acc[4][2] = 32 regs),
// SINGLE 12KB LDS buffer, m97 2-barrier loop: stage -> sync -> compute -> sync.
// Small acc + launch_bounds(256,6) targets 6 waves/SIMD (~75% occ) — the
// latency-bound fix (r1-r8 ran ~124 VGPR -> 4 waves/SIMD cap).
// z>=zsplit selects Bw2/bias2. flags==0 -> raw fp32 (split-K partial).
// ---------------------------------------------------------------------------
__global__ void __launch_bounds__(256, 6)
gemm_bt(const u16* __restrict__ A, int lda, Zm za,
        const u16* __restrict__ Bw, int ldb, Zm zb,
        const u16* __restrict__ Bw2, const float* __restrict__ bias2, int zsplit,
        void* __restrict__ Cv, int ldc, Zm zc,
        const float* __restrict__ bias, Zm zbias,
        const float* __restrict__ resid,
        float scale, int K, int flags)
{
  __shared__ __align__(16) u16 lA[128 * 32];   // 8KB
  __shared__ __align__(16) u16 lB[64 * 32];    // 4KB

  // T1: XCD-chunked block swizzle (bijective when nwg%8==0; all our grids are)
  const int gx = gridDim.x, gy = gridDim.y;
  int id = (blockIdx.z * gy + blockIdx.y) * gx + blockIdx.x;
  const int nwg = gx * gy * (int)gridDim.z;
  if ((nwg & 7) == 0) id = (id & 7) * (nwg >> 3) + (id >> 3);
  const int bx = id % gx;
  const int rest = id / gx;
  const int by = rest % gy;
  const int z0 = rest / gy;

  int zB = z0;
  const u16* Bsel = Bw;
  const float* bsel = bias;
  if (z0 >= zsplit) { Bsel = Bw2; bsel = bias2; zB = z0 - zsplit; }

  A    += zoff(za, z0);
  Bsel += zoff(zb, zB);

  const int bm = by * 128, bn = bx * 64;
  const int t = threadIdx.x;
  const int w = t >> 6, lane = t & 63;
  const int wr = w >> 1, wc = w & 1;

  const u16* ga0 = A    + (size_t)(bm + (t >> 2)) * lda + ((t & 3) << 3);
  const u16* ga1 = ga0 + (size_t)64 * lda;
  const u16* gb0 = Bsel + (size_t)(bn + (t >> 2)) * ldb + ((t & 3) << 3);

  f32x4 acc[4][2];
#pragma unroll
  for (int i = 0; i < 4; ++i)
#pragma unroll
    for (int j = 0; j < 2; ++j) acc[i][j] = (f32x4){0.f, 0.f, 0.f, 0.f};

  const int fr = lane & 15;
  const int kg = (lane >> 4) << 3;

  const int nt = K >> 5;
  for (int kt = 0; kt < nt; ++kt) {
    const int k0 = kt << 5;
    load_lds16(ga0 + k0, (char*)lA + (w << 10));
    load_lds16(ga1 + k0, (char*)lA + 4096 + (w << 10));
    load_lds16(gb0 + k0, (char*)lB + (w << 10));
    __syncthreads();                       // drains vmcnt: tile ready
    short8 af[4], bf[2];
#pragma unroll
    for (int mi = 0; mi < 4; ++mi)
      af[mi] = *(const short8*)(lA + (wr * 64 + mi * 16 + fr) * 32 + kg);
#pragma unroll
    for (int ni = 0; ni < 2; ++ni)
      bf[ni] = *(const short8*)(lB + (wc * 32 + ni * 16 + fr) * 32 + kg);
#pragma unroll
    for (int mi = 0; mi < 4; ++mi)
#pragma unroll
      for (int ni = 0; ni < 2; ++ni)
        MFMA16(acc[mi][ni], af[mi], bf[ni]);
    __syncthreads();                       // protect LDS before next stage
  }

  asm volatile("s_nop 7\n\ts_nop 7" ::: "memory");

  const ll co = zoff(zc, z0);
  const float* bz = (flags & (F_BCOL | F_BROW)) ? bsel + zoff(zbias, zB) : nullptr;
  const int r0 = (lane >> 4) << 2;
  const int c0 = lane & 15;
#pragma unroll
  for (int mi = 0; mi < 4; ++mi) {
#pragma unroll
    for (int ni = 0; ni < 2; ++ni) {
#pragma unroll
      for (int r = 0; r < 4; ++r) {
        const int grow = bm + wr * 64 + mi * 16 + r0 + r;
        const int gcol = bn + wc * 32 + ni * 16 + c0;
        float v = acc[mi][ni][r] * scale;
        if (flags & F_BCOL) v += bz[gcol];
        if (flags & F_BROW) v += bz[grow];
        if (flags & F_RELU) v = fmaxf(v, 0.f);
        if (flags & F_RESID) v += resid[(size_t)grow * ldc + gcol];
        const ll idx = co + (ll)grow * ldc + gcol;
        if (flags & F_BF16) ((u16*)Cv)[idx] = f2b(v);
        else                ((float*)Cv)[idx] = v;
      }
    }
  }
}

// ---------------------------------------------------------------------------
// Fused flash attention (round-6 version, best measured: 158 us).
// Grid 512 = 32 (h,b) x 16 q-tiles of 64 rows. 256 thr / 4 waves; wave owns
// 16 q-rows (softmax wave-local). KV-tile 128; QK/PV stream 128-chunks
// through qk_lds (bulk 12-load issue per chunk). P via p_lds stride 136.
// ---------------------------------------------------------------------------
__global__ void __launch_bounds__(256, 2)
fattn(const u16* __restrict__ qg, const u16* __restrict__ kg,
      const u16* __restrict__ vtg, u16* __restrict__ cat)
{
  __shared__ __align__(16) u16 qk_lds[192 * 128];  // Q [64][128] @0, K/vT [128][128] @8192 u16
  __shared__ __align__(16) u16 p_lds[64 * 136];

  int id = blockIdx.x;
  id = (id & 7) * 64 + (id >> 3);            // XCD-chunk: same hb stays on one XCD
  const int qt = id & 15;
  const int hb = id >> 4;                    // h*4 + b
  const int h = hb >> 2, b = hb & 3;

  const ll hbase = (ll)h * NB * NS * ND;
  const u16* Q  = qg  + hbase + ((ll)(b * NS + qt * 64)) * ND;
  const u16* Kp = kg  + hbase + (ll)b * NS * ND;
  const u16* VT = vtg + (ll)hb * ND * NS;    // [e][t], ld NS
  u16* Op = cat + ((ll)(b * NS + qt * 64)) * (NH * ND) + h * ND;

  const int t = threadIdx.x;
  const int w = t >> 6, lane = t & 63;
  const int fr = lane & 15, khi = lane >> 4;

  // stage geometry: 16 granules(16B)/row, row = t>>4, source col pre-swizzled
  const int srow = t >> 4;
  const int scol = (((t & 15) ^ (srow & 7)) << 3);   // u16 units
  char* const qkb = (char*)qk_lds;
  const int wslab = w << 10;

  f32x4 o[4][8];
#pragma unroll
  for (int ec = 0; ec < 4; ++ec)
#pragma unroll
    for (int nf = 0; nf < 8; ++nf) o[ec][nf] = (f32x4){0.f, 0.f, 0.f, 0.f};
  float m_r[4] = {-1e30f, -1e30f, -1e30f, -1e30f};
  float l_r[4] = {0.f, 0.f, 0.f, 0.f};

  for (int kv = 0; kv < 8; ++kv) {
    // ---------------- QK^T over 4 d-chunks of 128 ----------------
    f32x4 s[8];
#pragma unroll
    for (int nf = 0; nf < 8; ++nf) s[nf] = (f32x4){0.f, 0.f, 0.f, 0.f};

    for (int dch = 0; dch < 4; ++dch) {
#pragma unroll
      for (int i = 0; i < 4; ++i)                       // Q [64][128]
        load_lds16(Q + (ll)(i * 16 + srow) * ND + dch * 128 + scol,
                   qkb + i * 4096 + wslab);
#pragma unroll
      for (int i = 0; i < 8; ++i)                       // K [128][128]
        load_lds16(Kp + (ll)(kv * 128 + i * 16 + srow) * ND + dch * 128 + scol,
                   qkb + 16384 + i * 4096 + wslab);
      __syncthreads();
#pragma unroll
      for (int ks = 0; ks < 4; ++ks) {
        const int gq = (((4 * ks + khi) ^ (fr & 7)) << 3);   // swizzled col (u16)
        short8 aq = *(const short8*)(qk_lds + (w * 16 + fr) * 128 + gq);
#pragma unroll
        for (int nf = 0; nf < 8; ++nf) {
          short8 bk = *(const short8*)(qk_lds + 8192 + (nf * 16 + fr) * 128 + gq);
          MFMA16(s[nf], aq, bk);
        }
      }
      __syncthreads();
    }
    asm volatile("s_nop 7\n\ts_nop 7" ::: "memory");   // MFMA->VALU hazard

    // ------------- online softmax (rows = 4*khi+r, wave-local) -------------
#pragma unroll
    for (int r = 0; r < 4; ++r) {
      float v[8];
#pragma unroll
      for (int nf = 0; nf < 8; ++nf) v[nf] = s[nf][r] * 0.125f;
      float mx = v[0];
#pragma unroll
      for (int nf = 1; nf < 8; ++nf) mx = fmaxf(mx, v[nf]);
      mx = fmaxf(mx, __shfl_xor(mx, 1));
      mx = fmaxf(mx, __shfl_xor(mx, 2));
      mx = fmaxf(mx, __shfl_xor(mx, 4));
      mx = fmaxf(mx, __shfl_xor(mx, 8));
      const float mn = fmaxf(m_r[r], mx);
      const float f = __expf(m_r[r] - mn);
      m_r[r] = mn;
      float sum = 0.f;
#pragma unroll
      for (int nf = 0; nf < 8; ++nf) { v[nf] = __expf(v[nf] - mn); sum += v[nf]; }
      sum += __shfl_xor(sum, 1);
      sum += __shfl_xor(sum, 2);
      sum += __shfl_xor(sum, 4);
      sum += __shfl_xor(sum, 8);
      l_r[r] = l_r[r] * f + sum;
#pragma unroll
      for (int nf = 0; nf < 8; ++nf)
        p_lds[(w * 16 + 4 * khi + r) * 136 + nf * 16 + fr] = f2b(v[nf]);
#pragma unroll
      for (int ec = 0; ec < 4; ++ec)
#pragma unroll
        for (int nf = 0; nf < 8; ++nf) o[ec][nf][r] *= f;
    }

    // ---------------- PV over 4 e-chunks of 128 ----------------
#pragma unroll
    for (int ec = 0; ec < 4; ++ec) {
#pragma unroll
      for (int i = 0; i < 8; ++i)                       // vT chunk [128e][128t]
        load_lds16(VT + (ll)(ec * 128 + i * 16 + srow) * NS + kv * 128 + scol,
                   qkb + i * 4096 + wslab);
      __syncthreads();                                  // also orders P wr->rd
#pragma unroll
      for (int ks = 0; ks < 4; ++ks) {
        short8 ap = *(const short8*)(p_lds + (w * 16 + fr) * 136 + 32 * ks + 8 * khi);
        const int gv = (((4 * ks + khi) ^ (fr & 7)) << 3);
#pragma unroll
        for (int nf = 0; nf < 8; ++nf) {
          short8 bv8 = *(const short8*)(qk_lds + (nf * 16 + fr) * 128 + gv);
          MFMA16(o[ec][nf], ap, bv8);
        }
      }
      __syncthreads();
    }
  }

  asm volatile("s_nop 7\n\ts_nop 7" ::: "memory");
#pragma unroll
  for (int r = 0; r < 4; ++r) {
    const float inv = 1.f / l_r[r];
    const ll row = (ll)(w * 16 + 4 * khi + r) * (NH * ND);
#pragma unroll
    for (int ec = 0; ec < 4; ++ec)
#pragma unroll
      for (int nf = 0; nf < 8; ++nf)
        Op[row + ec * 128 + nf * 16 + fr] = f2b(o[ec][nf][r] * inv);
  }
}

// fused split-K reduce + bias + residual + LayerNorm; one wave/row, 4 rows/blk
__global__ void __launch_bounds__(256)
ln_red(const float* __restrict__ parts, int np, ll pstride,
       const float* __restrict__ bias, const float* __restrict__ resid,
       const float* __restrict__ g, const float* __restrict__ be,
       float* __restrict__ xout, u16* __restrict__ xbout)
{
  const int t = threadIdx.x, w = t >> 6, lane = t & 63;
  const ll row = (ll)blockIdx.x * 4 + w;
  const ll base = row * ND + lane * 8;
  float v[8];
  *(f32x4*)(v)     = *(const f32x4*)(resid + base);
  *(f32x4*)(v + 4) = *(const f32x4*)(resid + base + 4);
#pragma unroll
  for (int j = 0; j < 8; ++j) v[j] += bias[lane * 8 + j];
  for (int pIdx = 0; pIdx < np; ++pIdx) {
    const float* pp = parts + pIdx * pstride + base;
    f32x4 a0 = *(const f32x4*)(pp);
    f32x4 a1 = *(const f32x4*)(pp + 4);
    v[0] += a0.x; v[1] += a0.y; v[2] += a0.z; v[3] += a0.w;
    v[4] += a1.x; v[5] += a1.y; v[6] += a1.z; v[7] += a1.w;
  }
  float s = 0.f, q = 0.f;
#pragma unroll
  for (int j = 0; j < 8; ++j) { s += v[j]; q += v[j] * v[j]; }
#pragma unroll
  for (int o = 32; o >= 1; o >>= 1) { s += __shfl_xor(s, o); q += __shfl_xor(q, o); }
  const float mean = s * (1.f / ND);
  const float var  = q * (1.f / ND) - mean * mean;
  const float inv  = 1.f / sqrtf(var + 1e-5f);
#pragma unroll
  for (int j = 0; j < 8; ++j) {
    const int c = lane * 8 + j;
    const float y = (v[j] - mean) * inv * g[c] + be[c];
    xout[row * ND + c] = y;
    xbout[row * ND + c] = f2b(y);
  }
}

struct CvtJobs { const float* src[7]; u16* dst[7]; ll n[7]; };

__global__ void __launch_bounds__(256)
cvt7(CvtJobs j)
{
  const int z = blockIdx.y;
  const ll i = ((ll)blockIdx.x * 256 + threadIdx.x) * 4;
  if (i >= j.n[z]) return;
  f32x4 v = *(const f32x4*)(j.src[z] + i);
  u16x4 o;
  o.x = f2b(v.x); o.y = f2b(v.y); o.z = f2b(v.z); o.w = f2b(v.w);
  *(u16x4*)(j.dst[z] + i) = o;
}

// ---------------------------------------------------------------------------
extern "C" void kernel_launch(void* const* d_in, const int* in_sizes, int n_in,
                              void* d_out, int out_size, void* d_ws, size_t ws_size,
                              hipStream_t stream)
{
  (void)in_sizes; (void)n_in; (void)out_size; (void)ws_size;
  const float* x_in = (const float*)d_in[0];
  const float* Wq = (const float*)d_in[1];  const float* bq = (const float*)d_in[2];
  const float* Wk = (const float*)d_in[3];  const float* bk = (const float*)d_in[4];
  const float* Wv = (const float*)d_in[5];  const float* bv = (const float*)d_in[6];
  const float* Wo = (const float*)d_in[7];  const float* bo = (const float*)d_in[8];
  const float* W1 = (const float*)d_in[9];  const float* b1 = (const float*)d_in[10];
  const float* W2 = (const float*)d_in[11]; const float* b2 = (const float*)d_in[12];
  const float* ln1g = (const float*)d_in[13]; const float* ln1b = (const float*)d_in[14];
  const float* ln2g = (const float*)d_in[15]; const float* ln2b = (const float*)d_in[16];

  char* p = (char*)d_ws;
  auto alloc = [&](ll bytes) { char* r = p; p += (bytes + 255) & ~(ll)255; return r; };
  const ll nWq = (ll)NLAYER * NH * ND * ND;
  const ll nWo = (ll)NLAYER * ND * NH * ND;
  const ll nW1 = (ll)NLAYER * NDFF * ND;
  const ll nX  = (ll)NB * NS * ND;

  u16* wq_b = (u16*)alloc(nWq * 2);   // wq_b/wk_b adjacent, qb/kb adjacent
  u16* wk_b = (u16*)alloc(nWq * 2);
  u16* wv_b = (u16*)alloc(nWq * 2);
  u16* wo_b = (u16*)alloc(nWo * 2);
  u16* w1_b = (u16*)alloc(nW1 * 2);
  u16* w2_b = (u16*)alloc(nW1 * 2);
  u16* xb   = (u16*)alloc(nX * 2);
  u16* qb   = (u16*)alloc((ll)NH * NB * NS * ND * 2);  // [h][b*s][e]
  u16* kb   = (u16*)alloc((ll)NH * NB * NS * ND * 2);  // LIVE through fattn
  u16* vT   = (u16*)alloc((ll)NH * NB * ND * NS * 2);  // [h][b][e][t]
  u16* scb  = (u16*)alloc((ll)NB * NH * NS * NS * 2);  // cat (33.5MB) + parts (33.5MB)
  u16* cat = scb;                                      // [b][s][h*512+e]
  float* parts = (float*)(scb + (ll)NB * NS * NH * ND);
  u16* ffh = qb;                                       // overlay: q dead after fattn

  CvtJobs cj;
  cj.src[0] = Wq; cj.dst[0] = wq_b; cj.n[0] = nWq;
  cj.src[1] = Wk; cj.dst[1] = wk_b; cj.n[1] = nWq;
  cj.src[2] = Wv; cj.dst[2] = wv_b; cj.n[2] = nWq;
  cj.src[3] = Wo; cj.dst[3] = wo_b; cj.n[3] = nWo;
  cj.src[4] = W1; cj.dst[4] = w1_b; cj.n[4] = nW1;
  cj.src[5] = W2; cj.dst[5] = w2_b; cj.n[5] = nW1;
  cj.src[6] = x_in; cj.dst[6] = xb; cj.n[6] = nX;
  cvt7<<<dim3((unsigned)((nWq / 4 + 255) / 256), 7), 256, 0, stream>>>(cj);

  float* xf = (float*)d_out;           // fp32 residual stream lives in d_out
  const Zm Z0{1, 0, 0};
  const ll PSTR = nX;                  // split-K partial stride (elements)
  const int ZINF = 1 << 30;

  for (int i = 0; i < NLAYER; ++i) {
    const float* resid1 = (i == 0) ? x_in : xf;
    const ll woff = (ll)i * NH * ND * ND;

    // q+k projections merged: z<8 -> Wq/bq, z>=8 -> Wk/bk (C runs qb into kb)
    gemm_bt<<<dim3(ND/64, (NB*NS)/128, 2*NH), 256, 0, stream>>>(
        xb, ND, Z0,
        wq_b + woff, ND, Zm{1, (ll)ND * ND, 0},
        wk_b + woff, bk + (ll)i * NH * ND, NH,
        qb, ND, Zm{1, (ll)NB * NS * ND, 0},
        bq + (ll)i * NH * ND, Zm{1, ND, 0}, nullptr, 1.f, ND, F_BF16 | F_BCOL);

    // vT projection (operands swapped -> transposed out): z=h*4+b, C[e][t]
    gemm_bt<<<dim3(NS/64, ND/128, NH*NB), 256, 0, stream>>>(
        wv_b + woff, ND, Zm{NB, (ll)ND * ND, 0},
        xb, ND, Zm{NB, 0, (ll)NS * ND},
        xb, nullptr, ZINF,
        vT, NS, Zm{1, (ll)ND * NS, 0},
        bv + (ll)i * NH * ND, Zm{NB, ND, 0}, nullptr, 1.f, ND, F_BF16 | F_BROW);

    // fused flash attention: scores+softmax+PV -> cat
    fattn<<<dim3(512), 256, 0, stream>>>(qb, kb, vT, cat);

    // mha_out partials: split-K over K=4096 into 4 chunks of 1024
    gemm_bt<<<dim3(ND/64, (NB*NS)/128, 4), 256, 0, stream>>>(
        cat, NH * ND, Zm{1, 1024, 0},
        wo_b + (ll)i * ND * NH * ND, NH * ND, Zm{1, 1024, 0},
        wo_b, nullptr, ZINF,
        parts, ND, Zm{1, PSTR, 0},
        nullptr, Z0, nullptr, 1.f, 1024, 0);

    // LN1 = LayerNorm(resid + bo + sum parts)
    ln_red<<<dim3(NB * NS / 4), 256, 0, stream>>>(
        parts, 4, PSTR, bo + (ll)i * ND, resid1,
        ln1g + (ll)i * ND, ln1b + (ll)i * ND, xf, xb);

    // ffh = relu(x @ W1^T + b1)  (bf16)
    gemm_bt<<<dim3(NDFF/64, (NB*NS)/128, 1), 256, 0, stream>>>(
        xb, ND, Z0,
        w1_b + (ll)i * NDFF * ND, ND, Z0,
        w1_b, nullptr, ZINF,
        ffh, NDFF, Z0,
        b1 + (ll)i * NDFF, Z0, nullptr, 1.f, ND, F_BF16 | F_BCOL | F_RELU);

    // ff partials: split-K over K=2048 into 4 chunks of 512
    gemm_bt<<<dim3(ND/64, (NB*NS)/128, 4), 256, 0, stream>>>(
        ffh, NDFF, Zm{1, 512, 0},
        w2_b + (ll)i * ND * NDFF, NDFF, Zm{1, 512, 0},
        w2_b, nullptr, ZINF,
        parts, ND, Zm{1, PSTR, 0},
        nullptr, Z0, nullptr, 1.f, 512, 0);

    // LN2 = LayerNorm(x + b2 + sum parts)
    ln_red<<<dim3(NB * NS / 4), 256, 0, stream>>>(
        parts, 4, PSTR, b2 + (ll)i * ND, xf,
        ln2g + (ll)i * ND, ln2b + (ll)i * ND, xf, xb);
  }
}

// Round 10
// 670.677 us; speedup vs baseline: 1.1848x; 1.0560x over previous
//
#include <hip/hip_runtime.h>
#include <cstdint>
#include <cstddef>

#define NB 4
#define NS 1024
#define ND 512
#define NH 8
#define NLAYER 2
#define NDFF 2048

typedef __attribute__((ext_vector_type(8))) short short8;
typedef __attribute__((ext_vector_type(4))) float f32x4;
typedef __attribute__((ext_vector_type(4))) unsigned short u16x4;
typedef unsigned short u16;
typedef long long ll;

__device__ __forceinline__ float b2f(u16 u) {
  union { unsigned int i; float f; } x; x.i = ((unsigned int)u) << 16; return x.f;
}
__device__ __forceinline__ u16 f2b(float f) {  // RNE fp32 -> bf16
  union { float f; unsigned int i; } x; x.f = f;
  return (u16)((x.i + 0x7FFF + ((x.i >> 16) & 1)) >> 16);
}

struct Zm { int div; ll hi, lo; };   // per-z offset = (z/div)*hi + (z%div)*lo
__device__ __forceinline__ ll zoff(Zm m, int z) {
  return (ll)(z / m.div) * m.hi + (ll)(z % m.div) * m.lo;
}

enum { F_BF16 = 1, F_RELU = 2, F_BCOL = 4, F_BROW = 8, F_RESID = 16 };

// async global->LDS, 16B/lane; LDS dest is wave-uniform base + lane*16 (m104).
__device__ __forceinline__ void load_lds16(const void* g, void* s) {
  __builtin_amdgcn_global_load_lds(
      (const __attribute__((address_space(1))) void*)(uintptr_t)g,
      (__attribute__((address_space(3))) void*)(uint32_t)(uintptr_t)s, 16, 0, 0);
}

#define MFMA16(d, a, b) \
  asm volatile("v_mfma_f32_16x16x32_bf16 %0, %1, %2, %0" : "+v"(d) : "v"(a), "v"(b))

// ---------------------------------------------------------------------------
// BT-form GEMM (round-3/6 verified — best measured): C = scale*A*B^T (+post).
// 128x128 tile, BK=32 dbuf, 4 waves 2x2, one barrier per K-step.
// z>=zsplit selects Bw2/bias2. flags==0 -> raw fp32 (split-K partial).
// ---------------------------------------------------------------------------
__global__ void __launch_bounds__(256)
gemm_bt(const u16* __restrict__ A, int lda, Zm za,
        const u16* __restrict__ Bw, int ldb, Zm zb,
        const u16* __restrict__ Bw2, const float* __restrict__ bias2, int zsplit,
        void* __restrict__ Cv, int ldc, Zm zc,
        const float* __restrict__ bias, Zm zbias,
        const float* __restrict__ resid,
        float scale, int K, int flags)
{
  __shared__ __align__(16) char smem[2][16384];   // [buf][A:0..8191 | B:8192..]

  const int gx = gridDim.x, gy = gridDim.y;
  int id = (blockIdx.z * gy + blockIdx.y) * gx + blockIdx.x;
  const int nwg = gx * gy * (int)gridDim.z;
  if ((nwg & 7) == 0) id = (id & 7) * (nwg >> 3) + (id >> 3);
  const int bx = id % gx;
  const int rest = id / gx;
  const int by = rest % gy;
  const int z0 = rest / gy;

  int zB = z0;
  const u16* Bsel = Bw;
  const float* bsel = bias;
  if (z0 >= zsplit) { Bsel = Bw2; bsel = bias2; zB = z0 - zsplit; }

  A    += zoff(za, z0);
  Bsel += zoff(zb, zB);

  const int bm = by * 128, bn = bx * 128;
  const int t = threadIdx.x;
  const int w = t >> 6, lane = t & 63;
  const int wr = w >> 1, wc = w & 1;

  const u16* ga0 = A    + (size_t)(bm + (t >> 2)) * lda + ((t & 3) << 3);
  const u16* ga1 = ga0 + (size_t)64 * lda;
  const u16* gb0 = Bsel + (size_t)(bn + (t >> 2)) * ldb + ((t & 3) << 3);
  const u16* gb1 = gb0 + (size_t)64 * ldb;

  auto STAGE = [&](int sel, int kt) {
    const int k0 = kt << 5;
    char* sa = smem[sel] + (w << 10);
    char* sb = smem[sel] + 8192 + (w << 10);
    load_lds16(ga0 + k0, sa);
    load_lds16(ga1 + k0, sa + 4096);
    load_lds16(gb0 + k0, sb);
    load_lds16(gb1 + k0, sb + 4096);
  };

  f32x4 acc[4][4];
#pragma unroll
  for (int i = 0; i < 4; ++i)
#pragma unroll
    for (int j = 0; j < 4; ++j) acc[i][j] = (f32x4){0.f, 0.f, 0.f, 0.f};

  const int fr = lane & 15;
  const int kg = (lane >> 4) << 3;

  const int nt = K >> 5;
  STAGE(0, 0);
  __syncthreads();
  int cur = 0;
  for (int kt = 0; kt < nt; ++kt) {
    if (kt + 1 < nt) STAGE(cur ^ 1, kt + 1);
    const u16* la = (const u16*)smem[cur];
    const u16* lb = (const u16*)(smem[cur] + 8192);
    short8 af[4], bf[4];
#pragma unroll
    for (int mi = 0; mi < 4; ++mi)
      af[mi] = *(const short8*)(la + (wr * 64 + mi * 16 + fr) * 32 + kg);
#pragma unroll
    for (int ni = 0; ni < 4; ++ni)
      bf[ni] = *(const short8*)(lb + (wc * 64 + ni * 16 + fr) * 32 + kg);
#pragma unroll
    for (int mi = 0; mi < 4; ++mi)
#pragma unroll
      for (int ni = 0; ni < 4; ++ni)
        MFMA16(acc[mi][ni], af[mi], bf[ni]);
    __syncthreads();
    cur ^= 1;
  }

  asm volatile("s_nop 7\n\ts_nop 7" ::: "memory");

  const ll co = zoff(zc, z0);
  const float* bz = (flags & (F_BCOL | F_BROW)) ? bsel + zoff(zbias, zB) : nullptr;
  const int r0 = (lane >> 4) << 2;
  const int c0 = lane & 15;
#pragma unroll
  for (int mi = 0; mi < 4; ++mi) {
#pragma unroll
    for (int ni = 0; ni < 4; ++ni) {
#pragma unroll
      for (int r = 0; r < 4; ++r) {
        const int grow = bm + wr * 64 + mi * 16 + r0 + r;
        const int gcol = bn + wc * 64 + ni * 16 + c0;
        float v = acc[mi][ni][r] * scale;
        if (flags & F_BCOL) v += bz[gcol];
        if (flags & F_BROW) v += bz[grow];
        if (flags & F_RELU) v = fmaxf(v, 0.f);
        if (flags & F_RESID) v += resid[(size_t)grow * ldc + gcol];
        const ll idx = co + (ll)grow * ldc + gcol;
        if (flags & F_BF16) ((u16*)Cv)[idx] = f2b(v);
        else                ((float*)Cv)[idx] = v;
      }
    }
  }
}

// ---------------------------------------------------------------------------
// Fused flash attention v4 = round-6 schedule (best measured: 158 us) with
// two traffic cuts: (1) Q held in registers (16x short8/lane, loaded once;
// r7-verified numerics) — kills Q staging + Q LDS reads, LDS 65.5->49.4 KB;
// (2) P fragments hoisted: 4 ap reads per wave per kv (was 16), behind an
// lgkmcnt(0)+sched_barrier fence (rule 18, r8-verified).
// Grid 512 = 32 (h,b) x 16 q-tiles of 64 rows; 4 waves; wave owns 16 q-rows.
// KV-tile 128; kv_lds holds one [128][128] K- or vT-chunk at a time.
// ---------------------------------------------------------------------------
__global__ void __launch_bounds__(256, 2)
fattn(const u16* __restrict__ qg, const u16* __restrict__ kg,
      const u16* __restrict__ vtg, u16* __restrict__ cat)
{
  __shared__ __align__(16) u16 kv_lds[128 * 128];  // 32KB: K or vT chunk
  __shared__ __align__(16) u16 p_lds[64 * 136];    // 17KB (r6 layout)

  int id = blockIdx.x;
  id = (id & 7) * 64 + (id >> 3);            // XCD-chunk: same hb stays on one XCD
  const int qt = id & 15;
  const int hb = id >> 4;                    // h*4 + b
  const int h = hb >> 2, b = hb & 3;

  const ll hbase = (ll)h * NB * NS * ND;
  const u16* Q  = qg  + hbase + ((ll)(b * NS + qt * 64)) * ND;
  const u16* Kp = kg  + hbase + (ll)b * NS * ND;
  const u16* VT = vtg + (ll)hb * ND * NS;    // [e][t], ld NS
  u16* Op = cat + ((ll)(b * NS + qt * 64)) * (NH * ND) + h * ND;

  const int t = threadIdx.x;
  const int w = t >> 6, lane = t & 63;
  const int fr = lane & 15, khi = lane >> 4;

  // ---- Q in registers: qreg[dch*4+ks] covers k = dch*128+ks*32+khi*8.. ----
  short8 qreg[16];
#pragma unroll
  for (int s = 0; s < 16; ++s)
    qreg[s] = *(const short8*)(Q + (ll)(w * 16 + fr) * ND + s * 32 + khi * 8);

  // stage geometry: 16 granules(16B)/row, row = t>>4, source col pre-swizzled
  const int srow = t >> 4;
  const int scol = (((t & 15) ^ (srow & 7)) << 3);   // u16 units
  char* const qkb = (char*)kv_lds;
  const int wslab = w << 10;

  f32x4 o[4][8];
#pragma unroll
  for (int ec = 0; ec < 4; ++ec)
#pragma unroll
    for (int nf = 0; nf < 8; ++nf) o[ec][nf] = (f32x4){0.f, 0.f, 0.f, 0.f};
  float m_r[4] = {-1e30f, -1e30f, -1e30f, -1e30f};
  float l_r[4] = {0.f, 0.f, 0.f, 0.f};

  for (int kv = 0; kv < 8; ++kv) {
    // ---------------- QK^T over 4 d-chunks of 128 ----------------
    f32x4 s[8];
#pragma unroll
    for (int nf = 0; nf < 8; ++nf) s[nf] = (f32x4){0.f, 0.f, 0.f, 0.f};

    for (int dch = 0; dch < 4; ++dch) {
#pragma unroll
      for (int i = 0; i < 8; ++i)                       // K [128][128]
        load_lds16(Kp + (ll)(kv * 128 + i * 16 + srow) * ND + dch * 128 + scol,
                   qkb + i * 4096 + wslab);
      __syncthreads();
#pragma unroll
      for (int ks = 0; ks < 4; ++ks) {
        const short8 aq = qreg[dch * 4 + ks];
        const int gq = (((4 * ks + khi) ^ (fr & 7)) << 3);   // swizzled col
#pragma unroll
        for (int nf = 0; nf < 8; ++nf) {
          short8 bk = *(const short8*)(kv_lds + (nf * 16 + fr) * 128 + gq);
          MFMA16(s[nf], aq, bk);
        }
      }
      __syncthreads();
    }
    asm volatile("s_nop 7\n\ts_nop 7" ::: "memory");   // MFMA->VALU hazard

    // ------------- online softmax (rows = 4*khi+r, wave-local) -------------
#pragma unroll
    for (int r = 0; r < 4; ++r) {
      float v[8];
#pragma unroll
      for (int nf = 0; nf < 8; ++nf) v[nf] = s[nf][r] * 0.125f;
      float mx = v[0];
#pragma unroll
      for (int nf = 1; nf < 8; ++nf) mx = fmaxf(mx, v[nf]);
      mx = fmaxf(mx, __shfl_xor(mx, 1));
      mx = fmaxf(mx, __shfl_xor(mx, 2));
      mx = fmaxf(mx, __shfl_xor(mx, 4));
      mx = fmaxf(mx, __shfl_xor(mx, 8));
      const float mn = fmaxf(m_r[r], mx);
      const float f = __expf(m_r[r] - mn);
      m_r[r] = mn;
      float sum = 0.f;
#pragma unroll
      for (int nf = 0; nf < 8; ++nf) { v[nf] = __expf(v[nf] - mn); sum += v[nf]; }
      sum += __shfl_xor(sum, 1);
      sum += __shfl_xor(sum, 2);
      sum += __shfl_xor(sum, 4);
      sum += __shfl_xor(sum, 8);
      l_r[r] = l_r[r] * f + sum;
#pragma unroll
      for (int nf = 0; nf < 8; ++nf)
        p_lds[(w * 16 + 4 * khi + r) * 136 + nf * 16 + fr] = f2b(v[nf]);
#pragma unroll
      for (int ec = 0; ec < 4; ++ec)
#pragma unroll
        for (int nf = 0; nf < 8; ++nf) o[ec][nf][r] *= f;
    }

    // ap hoist: same-wave p_lds write->read; fence per rule 18
    asm volatile("s_waitcnt lgkmcnt(0)" ::: "memory");
    __builtin_amdgcn_sched_barrier(0);
    short8 ap[4];
#pragma unroll
    for (int ks = 0; ks < 4; ++ks)
      ap[ks] = *(const short8*)(p_lds + (w * 16 + fr) * 136 + 32 * ks + 8 * khi);

    // ---------------- PV over 4 e-chunks of 128 ----------------
#pragma unroll
    for (int ec = 0; ec < 4; ++ec) {
#pragma unroll
      for (int i = 0; i < 8; ++i)                       // vT chunk [128e][128t]
        load_lds16(VT + (ll)(ec * 128 + i * 16 + srow) * NS + kv * 128 + scol,
                   qkb + i * 4096 + wslab);
      __syncthreads();
#pragma unroll
      for (int ks = 0; ks < 4; ++ks) {
        const int gv = (((4 * ks + khi) ^ (fr & 7)) << 3);
#pragma unroll
        for (int nf = 0; nf < 8; ++nf) {
          short8 bv8 = *(const short8*)(kv_lds + (nf * 16 + fr) * 128 + gv);
          MFMA16(o[ec][nf], ap[ks], bv8);
        }
      }
      __syncthreads();
    }
  }

  asm volatile("s_nop 7\n\ts_nop 7" ::: "memory");
#pragma unroll
  for (int r = 0; r < 4; ++r) {
    const float inv = 1.f / l_r[r];
    const ll row = (ll)(w * 16 + 4 * khi + r) * (NH * ND);
#pragma unroll
    for (int ec = 0; ec < 4; ++ec)
#pragma unroll
      for (int nf = 0; nf < 8; ++nf)
        Op[row + ec * 128 + nf * 16 + fr] = f2b(o[ec][nf][r] * inv);
  }
}

// fused split-K reduce + bias + residual + LayerNorm; one wave/row, 4 rows/blk
__global__ void __launch_bounds__(256)
ln_red(const float* __restrict__ parts, int np, ll pstride,
       const float* __restrict__ bias, const float* __restrict__ resid,
       const float* __restrict__ g, const float* __restrict__ be,
       float* __restrict__ xout, u16* __restrict__ xbout)
{
  const int t = threadIdx.x, w = t >> 6, lane = t & 63;
  const ll row = (ll)blockIdx.x * 4 + w;
  const ll base = row * ND + lane * 8;
  float v[8];
  *(f32x4*)(v)     = *(const f32x4*)(resid + base);
  *(f32x4*)(v + 4) = *(const f32x4*)(resid + base + 4);
#pragma unroll
  for (int j = 0; j < 8; ++j) v[j] += bias[lane * 8 + j];
  for (int pIdx = 0; pIdx < np; ++pIdx) {
    const float* pp = parts + pIdx * pstride + base;
    f32x4 a0 = *(const f32x4*)(pp);
    f32x4 a1 = *(const f32x4*)(pp + 4);
    v[0] += a0.x; v[1] += a0.y; v[2] += a0.z; v[3] += a0.w;
    v[4] += a1.x; v[5] += a1.y; v[6] += a1.z; v[7] += a1.w;
  }
  float s = 0.f, q = 0.f;
#pragma unroll
  for (int j = 0; j < 8; ++j) { s += v[j]; q += v[j] * v[j]; }
#pragma unroll
  for (int o = 32; o >= 1; o >>= 1) { s += __shfl_xor(s, o); q += __shfl_xor(q, o); }
  const float mean = s * (1.f / ND);
  const float var  = q * (1.f / ND) - mean * mean;
  const float inv  = 1.f / sqrtf(var + 1e-5f);
#pragma unroll
  for (int j = 0; j < 8; ++j) {
    const int c = lane * 8 + j;
    const float y = (v[j] - mean) * inv * g[c] + be[c];
    xout[row * ND + c] = y;
    xbout[row * ND + c] = f2b(y);
  }
}

struct CvtJobs { const float* src[7]; u16* dst[7]; ll n[7]; };

__global__ void __launch_bounds__(256)
cvt7(CvtJobs j)
{
  const int z = blockIdx.y;
  const ll i = ((ll)blockIdx.x * 256 + threadIdx.x) * 4;
  if (i >= j.n[z]) return;
  f32x4 v = *(const f32x4*)(j.src[z] + i);
  u16x4 o;
  o.x = f2b(v.x); o.y = f2b(v.y); o.z = f2b(v.z); o.w = f2b(v.w);
  *(u16x4*)(j.dst[z] + i) = o;
}

// ---------------------------------------------------------------------------
extern "C" void kernel_launch(void* const* d_in, const int* in_sizes, int n_in,
                              void* d_out, int out_size, void* d_ws, size_t ws_size,
                              hipStream_t stream)
{
  (void)in_sizes; (void)n_in; (void)out_size; (void)ws_size;
  const float* x_in = (const float*)d_in[0];
  const float* Wq = (const float*)d_in[1];  const float* bq = (const float*)d_in[2];
  const float* Wk = (const float*)d_in[3];  const float* bk = (const float*)d_in[4];
  const float* Wv = (const float*)d_in[5];  const float* bv = (const float*)d_in[6];
  const float* Wo = (const float*)d_in[7];  const float* bo = (const float*)d_in[8];
  const float* W1 = (const float*)d_in[9];  const float* b1 = (const float*)d_in[10];
  const float* W2 = (const float*)d_in[11]; const float* b2 = (const float*)d_in[12];
  const float* ln1g = (const float*)d_in[13]; const float* ln1b = (const float*)d_in[14];
  const float* ln2g = (const float*)d_in[15]; const float* ln2b = (const float*)d_in[16];

  char* p = (char*)d_ws;
  auto alloc = [&](ll bytes) { char* r = p; p += (bytes + 255) & ~(ll)255; return r; };
  const ll nWq = (ll)NLAYER * NH * ND * ND;
  const ll nWo = (ll)NLAYER * ND * NH * ND;
  const ll nW1 = (ll)NLAYER * NDFF * ND;
  const ll nX  = (ll)NB * NS * ND;

  u16* wq_b = (u16*)alloc(nWq * 2);   // wq_b/wk_b adjacent, qb/kb adjacent
  u16* wk_b = (u16*)alloc(nWq * 2);
  u16* wv_b = (u16*)alloc(nWq * 2);
  u16* wo_b = (u16*)alloc(nWo * 2);
  u16* w1_b = (u16*)alloc(nW1 * 2);
  u16* w2_b = (u16*)alloc(nW1 * 2);
  u16* xb   = (u16*)alloc(nX * 2);
  u16* qb   = (u16*)alloc((ll)NH * NB * NS * ND * 2);  // [h][b*s][e]
  u16* kb   = (u16*)alloc((ll)NH * NB * NS * ND * 2);  // LIVE through fattn
  u16* vT   = (u16*)alloc((ll)NH * NB * ND * NS * 2);  // [h][b][e][t]
  u16* scb  = (u16*)alloc((ll)NB * NH * NS * NS * 2);  // cat (33.5MB) + parts (33.5MB)
  u16* cat = scb;                                      // [b][s][h*512+e]
  float* parts = (float*)(scb + (ll)NB * NS * NH * ND);
  u16* ffh = qb;                                       // overlay: q dead after fattn

  CvtJobs cj;
  cj.src[0] = Wq; cj.dst[0] = wq_b; cj.n[0] = nWq;
  cj.src[1] = Wk; cj.dst[1] = wk_b; cj.n[1] = nWq;
  cj.src[2] = Wv; cj.dst[2] = wv_b; cj.n[2] = nWq;
  cj.src[3] = Wo; cj.dst[3] = wo_b; cj.n[3] = nWo;
  cj.src[4] = W1; cj.dst[4] = w1_b; cj.n[4] = nW1;
  cj.src[5] = W2; cj.dst[5] = w2_b; cj.n[5] = nW1;
  cj.src[6] = x_in; cj.dst[6] = xb; cj.n[6] = nX;
  cvt7<<<dim3((unsigned)((nWq / 4 + 255) / 256), 7), 256, 0, stream>>>(cj);

  float* xf = (float*)d_out;           // fp32 residual stream lives in d_out
  const Zm Z0{1, 0, 0};
  const ll PSTR = nX;                  // split-K partial stride (elements)
  const int ZINF = 1 << 30;

  for (int i = 0; i < NLAYER; ++i) {
    const float* resid1 = (i == 0) ? x_in : xf;
    const ll woff = (ll)i * NH * ND * ND;

    // q+k projections merged: z<8 -> Wq/bq, z>=8 -> Wk/bk (C runs qb into kb)
    gemm_bt<<<dim3(ND/128, (NB*NS)/128, 2*NH), 256, 0, stream>>>(
        xb, ND, Z0,
        wq_b + woff, ND, Zm{1, (ll)ND * ND, 0},
        wk_b + woff, bk + (ll)i * NH * ND, NH,
        qb, ND, Zm{1, (ll)NB * NS * ND, 0},
        bq + (ll)i * NH * ND, Zm{1, ND, 0}, nullptr, 1.f, ND, F_BF16 | F_BCOL);

    // vT projection (operands swapped -> transposed out): z=h*4+b, C[e][t]
    gemm_bt<<<dim3(NS/128, ND/128, NH*NB), 256, 0, stream>>>(
        wv_b + woff, ND, Zm{NB, (ll)ND * ND, 0},
        xb, ND, Zm{NB, 0, (ll)NS * ND},
        xb, nullptr, ZINF,
        vT, NS, Zm{1, (ll)ND * NS, 0},
        bv + (ll)i * NH * ND, Zm{NB, ND, 0}, nullptr, 1.f, ND, F_BF16 | F_BROW);

    // fused flash attention: scores+softmax+PV -> cat
    fattn<<<dim3(512), 256, 0, stream>>>(qb, kb, vT, cat);

    // mha_out partials: split-K over K=4096 into 4 chunks of 1024
    gemm_bt<<<dim3(ND/128, (NB*NS)/128, 4), 256, 0, stream>>>(
        cat, NH * ND, Zm{1, 1024, 0},
        wo_b + (ll)i * ND * NH * ND, NH * ND, Zm{1, 1024, 0},
        wo_b, nullptr, ZINF,
        parts, ND, Zm{1, PSTR, 0},
        nullptr, Z0, nullptr, 1.f, 1024, 0);

    // LN1 = LayerNorm(resid + bo + sum parts)
    ln_red<<<dim3(NB * NS / 4), 256, 0, stream>>>(
        parts, 4, PSTR, bo + (ll)i * ND, resid1,
        ln1g + (ll)i * ND, ln1b + (ll)i * ND, xf, xb);

    // ffh = relu(x @ W1^T + b1)  (bf16)
    gemm_bt<<<dim3(NDFF/128, (NB*NS)/128, 1), 256, 0, stream>>>(
        xb, ND, Z0,
        w1_b + (ll)i * NDFF * ND, ND, Z0,
        w1_b, nullptr, ZINF,
        ffh, NDFF, Z0,
        b1 + (ll)i * NDFF, Z0, nullptr, 1.f, ND, F_BF16 | F_BCOL | F_RELU);

    // ff partials: split-K over K=2048 into 4 chunks of 512
    gemm_bt<<<dim3(ND/128, (NB*NS)/128, 4), 256, 0, stream>>>(
        ffh, NDFF, Zm{1, 512, 0},
        w2_b + (ll)i * ND * NDFF, NDFF, Zm{1, 512, 0},
        w2_b, nullptr, ZINF,
        parts, ND, Zm{1, PSTR, 0},
        nullptr, Z0, nullptr, 1.f, 512, 0);

    // LN2 = LayerNorm(x + b2 + sum parts)
    ln_red<<<dim3(NB * NS / 4), 256, 0, stream>>>(
        parts, 4, PSTR, b2 + (ll)i * ND, xf,
        ln2g + (ll)i * ND, ln2b + (ll)i * ND, xf, xb);
  }
}